// Round 16
// baseline (9892.420 us; speedup 1.0000x reference)
//
#include <hip/hip_runtime.h>

#define DP   256
#define DD   320
#define KK   10
#define CC   10
#define DOUT 64
#define SEQn 512
#define BB   32
#define SI   100
#define NSL  32     // dim slices (10 dims each)
#define NGR  8      // batch groups
#define BPG  4      // batches per group
#define NTH  640
#define DPS  10
#define RPS  100    // flat S-rows per slice

// pubA per group: uf[32 slices][40] (1280) + z[4 batches][96 c][32 slices] (12288)
#define GSZ   13568
#define HALF  (NGR*GSZ)
#define PUBA_OFF 2048

typedef float f4 __attribute__((ext_vector_type(4)));

__device__ __forceinline__ void llc_ld(f4* dst, const float* p) {
    f4 r;
    asm volatile("global_load_dwordx4 %0, %1, off sc0 sc1" : "=&v"(r) : "v"(p));
    asm volatile("s_waitcnt vmcnt(0)" ::: "memory");
    __builtin_amdgcn_sched_barrier(0);
    *dst = r;
}
__device__ __forceinline__ void llc_st(float* p, f4 v) {
    asm volatile("global_store_dwordx4 %0, %1, off sc0 sc1" :: "v"(p), "v"(v) : "memory");
}
__device__ __forceinline__ void llc_st1(float* p, float v) {
    asm volatile("global_store_dword %0, %1, off sc0 sc1" :: "v"(p), "v"(v) : "memory");
}

__global__ void prep_kernel(int* ctr) {
    int i = blockIdx.x * blockDim.x + threadIdx.x;
    if (i < 2048) ctr[i] = 0;
}

// 32-peer barrier, arrivals spread over 8 lines, 8-lane wave poll (r15 proven).
__device__ __forceinline__ void gbar8(int* base, int slice, int target) {
    asm volatile("s_waitcnt vmcnt(0)" ::: "memory");
    __syncthreads();
    if (threadIdx.x == 0)
        __hip_atomic_fetch_add(&base[(slice & 7) * 16], 1, __ATOMIC_RELEASE, __HIP_MEMORY_SCOPE_AGENT);
    if (threadIdx.x < 8) {
        for (;;) {
            int v = __hip_atomic_load(&base[threadIdx.x * 16], __ATOMIC_RELAXED, __HIP_MEMORY_SCOPE_AGENT);
            v += __shfl_xor(v, 1, 8);
            v += __shfl_xor(v, 2, 8);
            v += __shfl_xor(v, 4, 8);
            if (v >= target) break;
            __builtin_amdgcn_s_sleep(2);
        }
    }
    __syncthreads();
}

__global__ __launch_bounds__(NTH) void recur_kernel(
    const int* __restrict__ sentence, const int* __restrict__ speaker,
    const float* __restrict__ LutP, const float* __restrict__ LutS,
    const float* __restrict__ NaW,  const float* __restrict__ NaB,
    const float* __restrict__ NuW,  const float* __restrict__ NuB,
    const float* __restrict__ NoW,  const float* __restrict__ NoB,
    const float* __restrict__ FuW,  const float* __restrict__ FuB,
    const float* __restrict__ FoW,  const float* __restrict__ FoB,
    float* __restrict__ ws, const int* __restrict__ Tptr,
    float* __restrict__ out)
{
    const int tid  = threadIdx.x;
    const int s    = blockIdx.x & (NSL - 1);
    const int g    = blockIdx.x >> 5;
    const int dbase = s * DPS;
    const int rbase = s * RPS;
    int*  ctr  = (int*)ws + g * 128;
    float* pubA = ws + PUBA_OFF;

    const int c_   = tid >> 6;
    const int lane = tid & 63;

    __shared__ float xsE[BPG][3328];
    __shared__ float wNa[RPS][32];
    __shared__ float wNo[RPS][65];
    __shared__ float naT0[DPS][32];
    __shared__ float noT0[DPS][65];
    __shared__ float ufull[BPG][DD];
    __shared__ float colL[BPG][DD];
    __shared__ float ucol[BPG*DPS];
    __shared__ float zr[BPG*32];
    __shared__ float zor[BPG*DOUT];
    __shared__ float aout4[BPG][32];
    __shared__ float oprev4[BPG][DOUT];
    __shared__ float foNo4[BPG][DOUT];
    __shared__ float mu4[BPG][CC], sg4[BPG][CC], gg4[BPG][CC];
    __shared__ float alphaL[SEQn];
    __shared__ float hist4[BPG][104];
    __shared__ float idtF4[BPG][DP];
    __shared__ float identsh[BPG][DP];
    __shared__ float fos[BPG][RPS];
    __shared__ float nubO[DPS];
    __shared__ float nabL[32];
    __shared__ float zred[DOUT][9];
    __shared__ int   sentL4[BPG][SEQn];
    __shared__ short posidx4[BPG][SEQn];
    __shared__ int   vstart4[BPG][104];
    __shared__ int   vcnt[104];

    // ---------------- prologue ----------------
    for (int i = tid; i < RPS * 30; i += NTH) {
        int r = i / 30, c = i % 30;
        wNa[r][c] = NaW[(rbase + r) * 30 + c];
    }
    for (int i = tid; i < RPS * 64; i += NTH) {
        int r = i / 64, o = i % 64;
        wNo[r][o] = NoW[(rbase + r) * 64 + o];
    }
    if (tid < DPS * 30) { int dl = tid / 30, c = tid % 30; naT0[dl][c] = NaW[((dbase + dl) * KK) * 30 + c]; }
    if (tid < DPS * 64) { int dl = tid >> 6, o = tid & 63; noT0[dl][o] = NoW[((dbase + dl) * KK) * 64 + o]; }
    if (tid < DPS) nubO[tid] = NuB[dbase + tid];
    if (tid >= 16 && tid < 48) { int c = tid - 16; nabL[c] = (c < 30) ? NaB[c] : 0.f; }
    if (tid >= 64 && tid < 104) mu4[(tid - 64) / 10][(tid - 64) % 10] = 0.f;
    for (int i = tid; i < BPG * DP; i += NTH) {
        int j = i / DP, v = i % DP;
        identsh[j][v] = LutS[speaker[g * BPG + j] * DP + v];
    }
    for (int i = tid; i < BPG * SEQn; i += NTH)
        sentL4[i / SEQn][i % SEQn] = sentence[(g * BPG + i / SEQn) * SEQn + i % SEQn];
    __syncthreads();

    // Nu column weights (full, incl tap0) into registers
    float w[50];
    #pragma unroll
    for (int q = 0; q < 50; ++q)
        w[q] = NuW[(size_t)(lane * 50 + q) * DD + dbase + c_];

    // fo rows for this slice (per batch)
    for (int i = tid; i < BPG * RPS; i += NTH) {
        int j = i / RPS, r = i % RPS;
        float acc = FoB[rbase + r];
        for (int v = 0; v < DP; v += 8) {
            float wv[8];
            #pragma unroll
            for (int e = 0; e < 8; ++e) wv[e] = FoW[(v + e) * 3200 + rbase + r];
            #pragma unroll
            for (int e = 0; e < 8; ++e) acc += identsh[j][v + e] * wv[e];
        }
        fos[j][r] = acc;
    }
    // idt for all 4 batches
    for (int idx = tid; idx < BPG * DP; idx += NTH) {
        int j = idx / DP, d = idx % DP;
        float acc = FuB[d];
        for (int v = 0; v < DP; v += 8) {
            float wv[8];
            #pragma unroll
            for (int e = 0; e < 8; ++e) wv[e] = FuW[(v + e) * DP + d];
            #pragma unroll
            for (int e = 0; e < 8; ++e) acc += identsh[j][v + e] * wv[e];
        }
        idtF4[j][d] = tanhf(acc);
    }
    __syncthreads();
    // vocab bucketing, all 4 batches
    for (int j = 0; j < BPG; ++j) {
        if (tid < SI) { int cnt = 0; for (int q = 0; q < SEQn; ++q) cnt += (sentL4[j][q] == tid); vcnt[tid] = cnt; }
        __syncthreads();
        if (tid == 0) { int run = 0; for (int v = 0; v < SI; ++v) { vstart4[j][v] = run; run += vcnt[v]; } vstart4[j][SI] = run; }
        __syncthreads();
        if (tid < SI) { int k = vstart4[j][tid]; for (int q = 0; q < SEQn; ++q) if (sentL4[j][q] == tid) posidx4[j][k++] = (short)q; }
        __syncthreads();
    }
    // S0: every tap = [ident ; 0]
    for (int i = tid; i < BPG * 3200; i += NTH) {
        int j = i / 3200, row = i % 3200;
        int d = row / KK;
        xsE[j][(row / 50) * 52 + (row % 50)] = (d < DP) ? identsh[j][d] : 0.f;
    }
    __syncthreads();
    // za0 (full rows, tap0=ident) and zor0 (fo part)
    if (tid < 128) {
        int j = tid >> 5, c = tid & 31;
        float acc = 0.f;
        if (c < 30)
            for (int rr = 0; rr < RPS; ++rr) {
                int row = rbase + rr;
                acc += xsE[j][(row / 50) * 52 + (row % 50)] * wNa[rr][c];
            }
        zr[j * 32 + c] = acc;
    }
    if (tid >= 128 && tid < 384) {
        int t = tid - 128, j = t >> 6, o = t & 63;
        float acc = 0.f;
        for (int rr = 0; rr < RPS; ++rr) acc += fos[j][rr] * wNo[rr][o];
        zor[j * 64 + o] = acc;
    }
    __syncthreads();
    {
        float* pz = pubA + (size_t)g * GSZ + 1280;   // half 0
        if (tid < 128) { int j = tid >> 5, c = tid & 31; if (c < 30) llc_st1(pz + ((j * 96 + c) << 5) + s, zr[j * 32 + c]); }
        if (tid >= 128 && tid < 384) { int t = tid - 128; int j = t >> 6, o = t & 63; llc_st1(pz + ((j * 96 + 32 + o) << 5) + s, zor[j * 64 + o]); }
    }
    gbar8(ctr, s, 32 * 1);

    const int T = Tptr[0];

    for (int i = 0; i < T; ++i) {
        const int rh = i & 1, wh = rh ^ 1;
        const float* pa_r = pubA + (size_t)rh * HALF + (size_t)g * GSZ;
        float* pa_w = pubA + (size_t)wh * HALF + (size_t)g * GSZ;

        // ---- P1: one batched LLC read: z (tid<384, 8xf4) + uf (tid>=384) ----
        {
            f4 zv0,zv1,zv2,zv3,zv4,zv5,zv6,zv7;
            f4 ufa = {0,0,0,0}, ufb = {0,0,0,0};
            const bool hz = (tid < 384);
            const int zj = tid / 96, zc = tid % 96;
            if (hz) {
                const float* base = pa_r + 1280 + ((zj * 96 + zc) << 5);
                asm volatile("global_load_dwordx4 %0, %1, off sc0 sc1" : "=&v"(zv0) : "v"(base));
                asm volatile("global_load_dwordx4 %0, %1, off sc0 sc1" : "=&v"(zv1) : "v"(base + 4));
                asm volatile("global_load_dwordx4 %0, %1, off sc0 sc1" : "=&v"(zv2) : "v"(base + 8));
                asm volatile("global_load_dwordx4 %0, %1, off sc0 sc1" : "=&v"(zv3) : "v"(base + 12));
                asm volatile("global_load_dwordx4 %0, %1, off sc0 sc1" : "=&v"(zv4) : "v"(base + 16));
                asm volatile("global_load_dwordx4 %0, %1, off sc0 sc1" : "=&v"(zv5) : "v"(base + 20));
                asm volatile("global_load_dwordx4 %0, %1, off sc0 sc1" : "=&v"(zv6) : "v"(base + 24));
                asm volatile("global_load_dwordx4 %0, %1, off sc0 sc1" : "=&v"(zv7) : "v"(base + 28));
            }
            const bool hu = (i > 0 && tid >= 384);
            const int ui = tid - 384;
            if (hu) {
                asm volatile("global_load_dwordx4 %0, %1, off sc0 sc1" : "=&v"(ufa) : "v"(pa_r + ui * 4));
                if (ui < 64)
                    asm volatile("global_load_dwordx4 %0, %1, off sc0 sc1" : "=&v"(ufb) : "v"(pa_r + (ui + 256) * 4));
            }
            asm volatile("s_waitcnt vmcnt(0)" ::: "memory");
            __builtin_amdgcn_sched_barrier(0);
            if (hz) {
                float v = 0.f;
                v += zv0.x; v += zv0.y; v += zv0.z; v += zv0.w;
                v += zv1.x; v += zv1.y; v += zv1.z; v += zv1.w;
                v += zv2.x; v += zv2.y; v += zv2.z; v += zv2.w;
                v += zv3.x; v += zv3.y; v += zv3.z; v += zv3.w;
                v += zv4.x; v += zv4.y; v += zv4.z; v += zv4.w;
                v += zv5.x; v += zv5.y; v += zv5.z; v += zv5.w;
                v += zv6.x; v += zv6.y; v += zv6.z; v += zv6.w;
                v += zv7.x; v += zv7.y; v += zv7.z; v += zv7.w;
                if (zc < 30) {
                    aout4[zj][zc] = nabL[zc] + v;
                } else if (zc >= 32) {
                    int o = zc - 32;
                    if (i == 0) { foNo4[zj][o] = NoB[o] + v; oprev4[zj][o] = 0.f; }
                    else        oprev4[zj][o] = foNo4[zj][o] + v;
                }
            }
            if (hu) {
                #pragma unroll
                for (int e = 0; e < 4; ++e) {
                    int f = ui * 4 + e, p = f / 40, r = f % 40;
                    ufull[r / 10][p * 10 + r % 10] = ufa[e];
                }
                if (ui < 64) {
                    #pragma unroll
                    for (int e = 0; e < 4; ++e) {
                        int f = (ui + 256) * 4 + e, p = f / 40, r = f % 40;
                        ufull[r / 10][p * 10 + r % 10] = ufb[e];
                    }
                }
            }
        }
        __syncthreads();
        // ---- output write for o_{i-1} (block s==j writes batch g*4+j) ----
        if (i > 0 && s < BPG && tid < DOUT)
            out[((size_t)(i - 1) * BB + (g * BPG + s)) * DOUT + tid] = oprev4[s][tid];

        // ---- chain x4 (redundant, identical on all blocks) ----
        for (int j = 0; j < BPG; ++j) {
            if (tid < CC) {
                mu4[j][tid] += 0.05f * expf(aout4[j][tid]);
                sg4[j][tid] = expf(aout4[j][10 + tid]);
                float m = -1e30f;
                for (int q = 0; q < CC; ++q) m = fmaxf(m, aout4[j][20 + q]);
                float ss = 0.f;
                for (int q = 0; q < CC; ++q) ss += expf(aout4[j][20 + q] - m);
                gg4[j][tid] = expf(aout4[j][20 + tid] - m) / ss;
            }
            __syncthreads();
            if (tid < SEQn) {
                float J = (float)(tid + 1);
                float a = 0.f;
                #pragma unroll
                for (int c = 0; c < CC; ++c) { float dm = mu4[j][c] - J; a += gg4[j][c] * __expf(-0.5f * sg4[j][c] * dm * dm); }
                alphaL[tid] = a * 0.3989422917366028f;
            }
            __syncthreads();
            if (tid < SI) {
                float h = 0.f;
                for (int k = vstart4[j][tid]; k < vstart4[j][tid + 1]; ++k) h += alphaL[posidx4[j][k]];
                hist4[j][tid] = h;
            }
            __syncthreads();
        }
        // ---- col joint (LutP loaded once, 4 accumulators) ----
        if (tid < DP) {
            float a0 = idtF4[0][tid], a1 = idtF4[1][tid], a2 = idtF4[2][tid], a3 = idtF4[3][tid];
            for (int v = 0; v < SI; v += 10) {
                float wv[10];
                #pragma unroll
                for (int e = 0; e < 10; ++e) wv[e] = LutP[(v + e) * DP + tid];
                #pragma unroll
                for (int e = 0; e < 10; ++e) {
                    a0 += hist4[0][v + e] * wv[e];
                    a1 += hist4[1][v + e] * wv[e];
                    a2 += hist4[2][v + e] * wv[e];
                    a3 += hist4[3][v + e] * wv[e];
                }
            }
            colL[0][tid] = a0; colL[1][tid] = a1; colL[2][tid] = a2; colL[3][tid] = a3;
        } else if (tid < DP + DOUT) {
            int o = tid - DP;
            #pragma unroll
            for (int j = 0; j < BPG; ++j) colL[j][DP + o] = oprev4[j][o] * (1.0f / 30.0f);
        }
        __syncthreads();

        // ---- shift + insert: xsE := Sp_i = [C_i, u_{i-1}, old 1..8] ----
        for (int it = tid; it < BPG * DD; it += NTH) {
            int j = it / DD, d = it % DD;
            float* p = &xsE[j][(d / 5) * 52 + (d % 5) * 10];
            float t0 = p[0];
            float v1 = p[1], v2 = p[2], v3 = p[3], v4 = p[4], v5 = p[5], v6 = p[6], v7 = p[7], v8 = p[8];
            p[0] = colL[j][d];
            p[1] = (i == 0) ? t0 : ufull[j][d];
            p[2] = v1; p[3] = v2; p[4] = v3; p[5] = v4; p[6] = v5; p[7] = v6; p[8] = v7; p[9] = v8;
        }
        __syncthreads();

        // ---- E: final u for own 10 dims (weights in regs) ----
        {
            float accE[BPG];
            #pragma unroll
            for (int j = 0; j < BPG; ++j) {
                const float* xb = &xsE[j][lane * 52];
                float a = 0.f;
                #pragma unroll
                for (int qq = 0; qq < 12; ++qq) {
                    f4 x = *(const f4*)(xb + qq * 4);
                    a += x.x * w[qq * 4] + x.y * w[qq * 4 + 1] + x.z * w[qq * 4 + 2] + x.w * w[qq * 4 + 3];
                }
                a += xb[48] * w[48] + xb[49] * w[49];
                accE[j] = a;
            }
            #pragma unroll
            for (int j = 0; j < BPG; ++j)
                for (int off = 32; off; off >>= 1) accE[j] += __shfl_xor(accE[j], off, 64);
            if (lane == 0) {
                #pragma unroll
                for (int j = 0; j < BPG; ++j) ucol[j * DPS + c_] = accE[j] + nubO[c_];
            }
        }
        __syncthreads();

        // ---- za/zo: k>=1 rows + own-final-u tap0 fold ----
        if (tid < 128) {
            int j = tid >> 5, c = tid & 31;
            float acc = 0.f;
            if (c < 30) {
                for (int dd = 0; dd < DPS; ++dd) {
                    int rg = 2 * s + (dd >= 5);
                    int of = dd * 10 - (dd >= 5 ? 50 : 0);
                    const float* xb = &xsE[j][rg * 52 + of];
                    #pragma unroll
                    for (int k = 1; k < KK; ++k) acc += xb[k] * wNa[dd * 10 + k][c];
                }
                #pragma unroll
                for (int dl = 0; dl < DPS; ++dl) acc += ucol[j * DPS + dl] * naT0[dl][c];
            }
            zr[j * 32 + c] = acc;
        }
        if (tid >= 128 && tid < 384) {
            int t = tid - 128, j = t >> 6, o = t & 63;
            float acc = 0.f;
            for (int dd = 0; dd < DPS; ++dd) {
                int rg = 2 * s + (dd >= 5);
                int of = dd * 10 - (dd >= 5 ? 50 : 0);
                const float* xb = &xsE[j][rg * 52 + of];
                #pragma unroll
                for (int k = 1; k < KK; ++k) acc += xb[k] * wNo[dd * 10 + k][o];
            }
            #pragma unroll
            for (int dl = 0; dl < DPS; ++dl) acc += ucol[j * DPS + dl] * noT0[dl][o];
            zor[j * 64 + o] = acc;
        }
        __syncthreads();

        // ---- publish uf (per-slice) + za/zo (transposed scalar) ----
        if (tid < 10) llc_st(pa_w + s * 40 + tid * 4, *(f4*)&ucol[tid * 4]);
        {
            float* pz = pa_w + 1280;
            if (tid >= 64 && tid < 192) {
                int t = tid - 64, j = t >> 5, c = t & 31;
                if (c < 30) llc_st1(pz + ((j * 96 + c) << 5) + s, zr[j * 32 + c]);
            }
            if (tid >= 192 && tid < 448) {
                int t = tid - 192, j = t >> 6, o = t & 63;
                llc_st1(pz + ((j * 96 + 32 + o) << 5) + s, zor[j * 64 + o]);
            }
        }
        gbar8(ctr, s, 32 * (i + 2));
    }

    // ---- final output o_{T-1} (block s==j for batch j) ----
    if (s < BPG) {
        const float* pa_r = pubA + (size_t)(T & 1) * HALF + (size_t)g * GSZ;
        if (tid < 512) {
            int o = tid >> 3, q = tid & 7;
            f4 v; llc_ld(&v, pa_r + 1280 + ((s * 96 + 32 + o) << 5) + q * 4);
            zred[o][q] = ((v.x + v.y) + (v.z + v.w));
        }
        __syncthreads();
        if (tid < DOUT) {
            float v = foNo4[s][tid];
            #pragma unroll
            for (int q = 0; q < 8; ++q) v += zred[tid][q];
            out[((size_t)(T - 1) * BB + (g * BPG + s)) * DOUT + tid] = v;
        }
    }
}

extern "C" void kernel_launch(void* const* d_in, const int* in_sizes, int n_in,
                              void* d_out, int out_size, void* d_ws, size_t ws_size,
                              hipStream_t stream) {
    const int*   sentence = (const int*)d_in[0];
    const int*   speaker  = (const int*)d_in[1];
    const float* LutP = (const float*)d_in[2];
    const float* LutS = (const float*)d_in[3];
    const float* NaW  = (const float*)d_in[4];
    const float* NaB  = (const float*)d_in[5];
    const float* NuW  = (const float*)d_in[6];
    const float* NuB  = (const float*)d_in[7];
    const float* NoW  = (const float*)d_in[8];
    const float* NoB  = (const float*)d_in[9];
    const float* FuW  = (const float*)d_in[10];
    const float* FuB  = (const float*)d_in[11];
    const float* FoW  = (const float*)d_in[12];
    const float* FoB  = (const float*)d_in[13];
    const int*   Tptr = (const int*)d_in[14];
    float* ws   = (float*)d_ws;
    float* outp = (float*)d_out;

    hipLaunchKernelGGL(prep_kernel, dim3(2), dim3(1024), 0, stream, (int*)d_ws);
    hipLaunchKernelGGL(recur_kernel, dim3(NSL * NGR), dim3(NTH), 0, stream,
                       sentence, speaker, LutP, LutS, NaW, NaB,
                       NuW, NuB, NoW, NoB, FuW, FuB, FoW, FoB,
                       ws, Tptr, outp);
}

// Round 17
// 8012.378 us; speedup vs baseline: 1.2346x; 1.2346x over previous
//
#include <hip/hip_runtime.h>

#define DP   256
#define DD   320
#define KK   10
#define CC   10
#define DOUT 64
#define SEQn 512
#define BB   32
#define SI   100
#define NSL  32
#define NGR  8
#define BPG  4
#define NTH  640
#define DPS  10
#define RPS  100

// ws layout (words): [0,2048) barrier counters; [2048,14336) zacc (3 bufs x 8 grp x 4 batch x 128);
// [14336, ...) uf halves: 2 x NGR x 1280
#define ZACC_OFF 2048
#define ZHALF    (NGR*BPG*128)
#define UF_OFF   (ZACC_OFF + 3*ZHALF)
#define UFH      (NGR*1280)

typedef float f4 __attribute__((ext_vector_type(4)));

__device__ __forceinline__ void llc_ld(f4* dst, const float* p) {
    f4 r;
    asm volatile("global_load_dwordx4 %0, %1, off sc0 sc1" : "=&v"(r) : "v"(p));
    asm volatile("s_waitcnt vmcnt(0)" ::: "memory");
    __builtin_amdgcn_sched_barrier(0);
    *dst = r;
}
__device__ __forceinline__ void llc_st(float* p, f4 v) {
    asm volatile("global_store_dwordx4 %0, %1, off sc0 sc1" :: "v"(p), "v"(v) : "memory");
}
__device__ __forceinline__ void llc_add(float* p, float v) {
    __hip_atomic_fetch_add(p, v, __ATOMIC_RELAXED, __HIP_MEMORY_SCOPE_AGENT);
}

__global__ void prep_kernel(int* ctr) {
    int i = blockIdx.x * blockDim.x + threadIdx.x;
    if (i < UF_OFF) ctr[i] = 0;   // counters + all 3 zacc buffers
}

// 32-peer barrier, arrivals on 8 lines, 8-lane wave poll (r15 proven).
__device__ __forceinline__ void gbar8(int* base, int slice, int target) {
    asm volatile("s_waitcnt vmcnt(0)" ::: "memory");
    __syncthreads();
    if (threadIdx.x == 0)
        __hip_atomic_fetch_add(&base[(slice & 7) * 16], 1, __ATOMIC_RELEASE, __HIP_MEMORY_SCOPE_AGENT);
    if (threadIdx.x < 8) {
        for (;;) {
            int v = __hip_atomic_load(&base[threadIdx.x * 16], __ATOMIC_RELAXED, __HIP_MEMORY_SCOPE_AGENT);
            v += __shfl_xor(v, 1, 8);
            v += __shfl_xor(v, 2, 8);
            v += __shfl_xor(v, 4, 8);
            if (v >= target) break;
            __builtin_amdgcn_s_sleep(2);
        }
    }
    __syncthreads();
}

__global__ __launch_bounds__(NTH) void recur_kernel(
    const int* __restrict__ sentence, const int* __restrict__ speaker,
    const float* __restrict__ LutP, const float* __restrict__ LutS,
    const float* __restrict__ NaW,  const float* __restrict__ NaB,
    const float* __restrict__ NuW,  const float* __restrict__ NuB,
    const float* __restrict__ NoW,  const float* __restrict__ NoB,
    const float* __restrict__ FuW,  const float* __restrict__ FuB,
    const float* __restrict__ FoW,  const float* __restrict__ FoB,
    float* __restrict__ ws, const int* __restrict__ Tptr,
    float* __restrict__ out)
{
    const int tid  = threadIdx.x;
    const int s    = blockIdx.x & (NSL - 1);
    const int g    = blockIdx.x >> 5;
    const int dbase = s * DPS;
    const int rbase = s * RPS;
    int*  ctr  = (int*)ws + g * 128;
    float* zA  = ws + ZACC_OFF;
    float* pubU = ws + UF_OFF;

    const int c_   = tid >> 6;
    const int lane = tid & 63;

    __shared__ float xsE[BPG][3328];
    __shared__ float wNa[RPS][32];
    __shared__ float wNo[RPS][65];
    __shared__ float naT0[DPS][32];
    __shared__ float noT0[DPS][65];
    __shared__ float ufull[BPG][DD];
    __shared__ float colL[BPG][DD];
    __shared__ float ucol[BPG*DPS];
    __shared__ float zr[BPG*32];
    __shared__ float zor[BPG*DOUT];
    __shared__ float zred4[BPG][96];
    __shared__ float aout4[BPG][32];
    __shared__ float oprev4[BPG][DOUT];
    __shared__ float foNo4[BPG][DOUT];
    __shared__ float mu4[BPG][CC], sg4[BPG][CC], gg4[BPG][CC];
    __shared__ float alpha4[BPG][SEQn];
    __shared__ float hist4[BPG][104];
    __shared__ float idtF4[BPG][DP];
    __shared__ float identsh[BPG][DP];
    __shared__ float fos[BPG][RPS];
    __shared__ float nubO[DPS];
    __shared__ float nabL[32];
    __shared__ short sentL4[BPG][SEQn];
    __shared__ short posidx4[BPG][SEQn];
    __shared__ int   vstart4[BPG][104];
    __shared__ int   vcnt[104];

    // ---------------- prologue ----------------
    for (int i = tid; i < RPS * 30; i += NTH) {
        int r = i / 30, c = i % 30;
        wNa[r][c] = NaW[(rbase + r) * 30 + c];
    }
    for (int i = tid; i < RPS * 64; i += NTH) {
        int r = i / 64, o = i % 64;
        wNo[r][o] = NoW[(rbase + r) * 64 + o];
    }
    if (tid < DPS * 30) { int dl = tid / 30, c = tid % 30; naT0[dl][c] = NaW[((dbase + dl) * KK) * 30 + c]; }
    if (tid < DPS * 64) { int dl = tid >> 6, o = tid & 63; noT0[dl][o] = NoW[((dbase + dl) * KK) * 64 + o]; }
    if (tid < DPS) nubO[tid] = NuB[dbase + tid];
    if (tid >= 16 && tid < 48) { int c = tid - 16; nabL[c] = (c < 30) ? NaB[c] : 0.f; }
    if (tid >= 64 && tid < 104) mu4[(tid - 64) / 10][(tid - 64) % 10] = 0.f;
    for (int i = tid; i < BPG * DP; i += NTH) {
        int j = i / DP, v = i % DP;
        identsh[j][v] = LutS[speaker[g * BPG + j] * DP + v];
    }
    for (int i = tid; i < BPG * SEQn; i += NTH)
        sentL4[i / SEQn][i % SEQn] = (short)sentence[(g * BPG + i / SEQn) * SEQn + i % SEQn];
    __syncthreads();

    // Nu column weights (full, incl tap0) into registers
    float w[50];
    #pragma unroll
    for (int q = 0; q < 50; ++q)
        w[q] = NuW[(size_t)(lane * 50 + q) * DD + dbase + c_];

    // fo rows for this slice (per batch)
    for (int i = tid; i < BPG * RPS; i += NTH) {
        int j = i / RPS, r = i % RPS;
        float acc = FoB[rbase + r];
        for (int v = 0; v < DP; v += 8) {
            float wv[8];
            #pragma unroll
            for (int e = 0; e < 8; ++e) wv[e] = FoW[(v + e) * 3200 + rbase + r];
            #pragma unroll
            for (int e = 0; e < 8; ++e) acc += identsh[j][v + e] * wv[e];
        }
        fos[j][r] = acc;
    }
    // idt for all 4 batches
    for (int idx = tid; idx < BPG * DP; idx += NTH) {
        int j = idx / DP, d = idx % DP;
        float acc = FuB[d];
        for (int v = 0; v < DP; v += 8) {
            float wv[8];
            #pragma unroll
            for (int e = 0; e < 8; ++e) wv[e] = FuW[(v + e) * DP + d];
            #pragma unroll
            for (int e = 0; e < 8; ++e) acc += identsh[j][v + e] * wv[e];
        }
        idtF4[j][d] = tanhf(acc);
    }
    __syncthreads();
    // vocab bucketing, all 4 batches
    for (int j = 0; j < BPG; ++j) {
        if (tid < SI) { int cnt = 0; for (int q = 0; q < SEQn; ++q) cnt += (sentL4[j][q] == tid); vcnt[tid] = cnt; }
        __syncthreads();
        if (tid == 0) { int run = 0; for (int v = 0; v < SI; ++v) { vstart4[j][v] = run; run += vcnt[v]; } vstart4[j][SI] = run; }
        __syncthreads();
        if (tid < SI) { int k = vstart4[j][tid]; for (int q = 0; q < SEQn; ++q) if (sentL4[j][q] == tid) posidx4[j][k++] = (short)q; }
        __syncthreads();
    }
    // S0
    for (int i = tid; i < BPG * 3200; i += NTH) {
        int j = i / 3200, row = i % 3200;
        int d = row / KK;
        xsE[j][(row / 50) * 52 + (row % 50)] = (d < DP) ? identsh[j][d] : 0.f;
    }
    __syncthreads();
    // za0 (full rows, tap0=ident) and zo0 (fo part) -> atomic add into buf0
    if (tid < 128) {
        int j = tid >> 5, c = tid & 31;
        float acc = 0.f;
        if (c < 30)
            for (int rr = 0; rr < RPS; ++rr) {
                int row = rbase + rr;
                acc += xsE[j][(row / 50) * 52 + (row % 50)] * wNa[rr][c];
            }
        zr[j * 32 + c] = acc;
    }
    if (tid >= 128 && tid < 384) {
        int t = tid - 128, j = t >> 6, o = t & 63;
        float acc = 0.f;
        for (int rr = 0; rr < RPS; ++rr) acc += fos[j][rr] * wNo[rr][o];
        zor[j * 64 + o] = acc;
    }
    __syncthreads();
    {
        float* z0 = zA + (size_t)g * BPG * 128;
        if (tid < 128) { int j = tid >> 5, c = tid & 31; if (c < 30) llc_add(z0 + j * 128 + c, zr[j * 32 + c]); }
        if (tid >= 128 && tid < 384) { int t = tid - 128, j = t >> 6, o = t & 63; llc_add(z0 + j * 128 + 32 + o, zor[j * 64 + o]); }
    }
    gbar8(ctr, s, 32 * 1);

    const int T = Tptr[0];

    for (int i = 0; i < T; ++i) {
        const float* z_r = zA + (size_t)(i % 3) * ZHALF + (size_t)g * BPG * 128;
        float* z_w = zA + (size_t)((i + 1) % 3) * ZHALF + (size_t)g * BPG * 128;
        float* z_z = zA + (size_t)((i + 2) % 3) * ZHALF + (size_t)g * BPG * 128;
        const float* uf_r = pubU + (size_t)(i & 1) * UFH + (size_t)g * 1280;
        float* uf_w = pubU + (size_t)((i + 1) & 1) * UFH + (size_t)g * 1280;

        // ---- P1: batched read of reduced z (tid<96) + uf (tid>=384) ----
        {
            f4 zv = {0,0,0,0}, ufa = {0,0,0,0}, ufb = {0,0,0,0};
            const bool hz = (tid < 96);
            if (hz) {
                const float* p = z_r + (tid / 24) * 128 + (tid % 24) * 4;
                asm volatile("global_load_dwordx4 %0, %1, off sc0 sc1" : "=&v"(zv) : "v"(p));
            }
            const bool hu = (i > 0 && tid >= 384);
            const int ui = tid - 384;
            if (hu) {
                asm volatile("global_load_dwordx4 %0, %1, off sc0 sc1" : "=&v"(ufa) : "v"(uf_r + ui * 4));
                if (ui < 64)
                    asm volatile("global_load_dwordx4 %0, %1, off sc0 sc1" : "=&v"(ufb) : "v"(uf_r + (ui + 256) * 4));
            }
            asm volatile("s_waitcnt vmcnt(0)" ::: "memory");
            __builtin_amdgcn_sched_barrier(0);
            if (hz) *(f4*)&zred4[tid / 24][(tid % 24) * 4] = zv;
            if (hu) {
                #pragma unroll
                for (int e = 0; e < 4; ++e) {
                    int f = ui * 4 + e, p = f / 40, r = f % 40;
                    ufull[r / 10][p * 10 + r % 10] = ufa[e];
                }
                if (ui < 64) {
                    #pragma unroll
                    for (int e = 0; e < 4; ++e) {
                        int f = (ui + 256) * 4 + e, p = f / 40, r = f % 40;
                        ufull[r / 10][p * 10 + r % 10] = ufb[e];
                    }
                }
            }
        }
        __syncthreads();
        // ---- aout / oprev from reduced z ----
        if (tid < 120) {
            int j = tid / 30, c = tid % 30;
            aout4[j][c] = nabL[c] + zred4[j][c];
        } else if (tid >= 128 && tid < 384) {
            int t = tid - 128, j = t >> 6, o = t & 63;
            if (i == 0) { foNo4[j][o] = NoB[o] + zred4[j][32 + o]; oprev4[j][o] = 0.f; }
            else        oprev4[j][o] = foNo4[j][o] + zred4[j][32 + o];
        }
        __syncthreads();
        if (i > 0 && s < BPG && tid < DOUT)
            out[((size_t)(i - 1) * BB + (g * BPG + s)) * DOUT + tid] = oprev4[s][tid];

        // ---- redundant chain, all 4 batches in parallel ----
        if (tid < 40) {
            int j = tid / 10, c = tid % 10;
            mu4[j][c] += 0.05f * expf(aout4[j][c]);
            sg4[j][c] = expf(aout4[j][10 + c]);
            float m = -1e30f;
            for (int q = 0; q < CC; ++q) m = fmaxf(m, aout4[j][20 + q]);
            float ss = 0.f;
            for (int q = 0; q < CC; ++q) ss += expf(aout4[j][20 + q] - m);
            gg4[j][c] = expf(aout4[j][20 + c] - m) / ss;
        }
        __syncthreads();
        if (tid < SEQn) {
            float J = (float)(tid + 1);
            #pragma unroll
            for (int j = 0; j < BPG; ++j) {
                float a = 0.f;
                #pragma unroll
                for (int c = 0; c < CC; ++c) { float dm = mu4[j][c] - J; a += gg4[j][c] * __expf(-0.5f * sg4[j][c] * dm * dm); }
                alpha4[j][tid] = a * 0.3989422917366028f;
            }
        }
        __syncthreads();
        if (tid < 400) {
            int j = tid / 100, v = tid % 100;
            float h = 0.f;
            for (int k = vstart4[j][v]; k < vstart4[j][v + 1]; ++k) h += alpha4[j][posidx4[j][k]];
            hist4[j][v] = h;
        }
        __syncthreads();
        // ---- col joint (LutP loaded once, 4 accumulators) ----
        if (tid < DP) {
            float a0 = idtF4[0][tid], a1 = idtF4[1][tid], a2 = idtF4[2][tid], a3 = idtF4[3][tid];
            for (int v = 0; v < SI; v += 10) {
                float wv[10];
                #pragma unroll
                for (int e = 0; e < 10; ++e) wv[e] = LutP[(v + e) * DP + tid];
                #pragma unroll
                for (int e = 0; e < 10; ++e) {
                    a0 += hist4[0][v + e] * wv[e];
                    a1 += hist4[1][v + e] * wv[e];
                    a2 += hist4[2][v + e] * wv[e];
                    a3 += hist4[3][v + e] * wv[e];
                }
            }
            colL[0][tid] = a0; colL[1][tid] = a1; colL[2][tid] = a2; colL[3][tid] = a3;
        } else if (tid < DP + DOUT) {
            int o = tid - DP;
            #pragma unroll
            for (int j = 0; j < BPG; ++j) colL[j][DP + o] = oprev4[j][o] * (1.0f / 30.0f);
        }
        __syncthreads();

        // ---- shift + insert: xsE := Sp_i ----
        for (int it = tid; it < BPG * DD; it += NTH) {
            int j = it / DD, d = it % DD;
            float* p = &xsE[j][(d / 5) * 52 + (d % 5) * 10];
            float t0 = p[0];
            float v1 = p[1], v2 = p[2], v3 = p[3], v4 = p[4], v5 = p[5], v6 = p[6], v7 = p[7], v8 = p[8];
            p[0] = colL[j][d];
            p[1] = (i == 0) ? t0 : ufull[j][d];
            p[2] = v1; p[3] = v2; p[4] = v3; p[5] = v4; p[6] = v5; p[7] = v6; p[8] = v7; p[9] = v8;
        }
        __syncthreads();

        // ---- E: final u for own 10 dims ----
        {
            float accE[BPG];
            #pragma unroll
            for (int j = 0; j < BPG; ++j) {
                const float* xb = &xsE[j][lane * 52];
                float a = 0.f;
                #pragma unroll
                for (int qq = 0; qq < 12; ++qq) {
                    f4 x = *(const f4*)(xb + qq * 4);
                    a += x.x * w[qq * 4] + x.y * w[qq * 4 + 1] + x.z * w[qq * 4 + 2] + x.w * w[qq * 4 + 3];
                }
                a += xb[48] * w[48] + xb[49] * w[49];
                accE[j] = a;
            }
            #pragma unroll
            for (int j = 0; j < BPG; ++j)
                for (int off = 32; off; off >>= 1) accE[j] += __shfl_xor(accE[j], off, 64);
            if (lane == 0) {
                #pragma unroll
                for (int j = 0; j < BPG; ++j) ucol[j * DPS + c_] = accE[j] + nubO[c_];
            }
        }
        __syncthreads();

        // ---- za/zo: k>=1 rows + own-final-u tap0 fold ----
        if (tid < 128) {
            int j = tid >> 5, c = tid & 31;
            float acc = 0.f;
            if (c < 30) {
                for (int dd = 0; dd < DPS; ++dd) {
                    int rg = 2 * s + (dd >= 5);
                    int of = dd * 10 - (dd >= 5 ? 50 : 0);
                    const float* xb = &xsE[j][rg * 52 + of];
                    #pragma unroll
                    for (int k = 1; k < KK; ++k) acc += xb[k] * wNa[dd * 10 + k][c];
                }
                #pragma unroll
                for (int dl = 0; dl < DPS; ++dl) acc += ucol[j * DPS + dl] * naT0[dl][c];
            }
            zr[j * 32 + c] = acc;
        }
        if (tid >= 128 && tid < 384) {
            int t = tid - 128, j = t >> 6, o = t & 63;
            float acc = 0.f;
            for (int dd = 0; dd < DPS; ++dd) {
                int rg = 2 * s + (dd >= 5);
                int of = dd * 10 - (dd >= 5 ? 50 : 0);
                const float* xb = &xsE[j][rg * 52 + of];
                #pragma unroll
                for (int k = 1; k < KK; ++k) acc += xb[k] * wNo[dd * 10 + k][o];
            }
            #pragma unroll
            for (int dl = 0; dl < DPS; ++dl) acc += ucol[j * DPS + dl] * noT0[dl][o];
            zor[j * 64 + o] = acc;
        }
        __syncthreads();

        // ---- publish uf, atomic-add za/zo, zero stale buf ----
        if (tid < 10) llc_st(uf_w + s * 40 + tid * 4, *(f4*)&ucol[tid * 4]);
        else if (tid >= 64 && tid < 192) {
            int t = tid - 64, j = t >> 5, c = t & 31;
            if (c < 30) llc_add(z_w + j * 128 + c, zr[j * 32 + c]);
        }
        else if (tid >= 192 && tid < 448) {
            int t = tid - 192, j = t >> 6, o = t & 63;
            llc_add(z_w + j * 128 + 32 + o, zor[j * 64 + o]);
        }
        else if (tid >= 448 && tid < 544) {
            int idx = tid - 448;
            f4 zz = {0.f, 0.f, 0.f, 0.f};
            llc_st(z_z + (idx / 24) * 128 + (idx % 24) * 4, zz);
        }
        gbar8(ctr, s, 32 * (i + 2));
    }

    // ---- final output o_{T-1} ----
    if (s < BPG) {
        const float* zF = zA + (size_t)(T % 3) * ZHALF + (size_t)g * BPG * 128;
        if (tid < 16) {
            f4 v; llc_ld(&v, zF + s * 128 + 32 + tid * 4);
            *(f4*)&zr[tid * 4] = v;
        }
        __syncthreads();
        if (tid < DOUT)
            out[((size_t)(T - 1) * BB + (g * BPG + s)) * DOUT + tid] = foNo4[s][tid] + zr[tid];
    }
}

extern "C" void kernel_launch(void* const* d_in, const int* in_sizes, int n_in,
                              void* d_out, int out_size, void* d_ws, size_t ws_size,
                              hipStream_t stream) {
    const int*   sentence = (const int*)d_in[0];
    const int*   speaker  = (const int*)d_in[1];
    const float* LutP = (const float*)d_in[2];
    const float* LutS = (const float*)d_in[3];
    const float* NaW  = (const float*)d_in[4];
    const float* NaB  = (const float*)d_in[5];
    const float* NuW  = (const float*)d_in[6];
    const float* NuB  = (const float*)d_in[7];
    const float* NoW  = (const float*)d_in[8];
    const float* NoB  = (const float*)d_in[9];
    const float* FuW  = (const float*)d_in[10];
    const float* FuB  = (const float*)d_in[11];
    const float* FoW  = (const float*)d_in[12];
    const float* FoB  = (const float*)d_in[13];
    const int*   Tptr = (const int*)d_in[14];
    float* ws   = (float*)d_ws;
    float* outp = (float*)d_out;

    hipLaunchKernelGGL(prep_kernel, dim3(14), dim3(1024), 0, stream, (int*)d_ws);
    hipLaunchKernelGGL(recur_kernel, dim3(NSL * NGR), dim3(NTH), 0, stream,
                       sentence, speaker, LutP, LutS, NaW, NaB,
                       NuW, NuB, NoW, NoB, FuW, FuB, FoW, FoB,
                       ws, Tptr, outp);
}

// Round 18
// 4674.449 us; speedup vs baseline: 2.1163x; 1.7141x over previous
//
#include <hip/hip_runtime.h>

#define DP   256
#define DD   320
#define KK   10
#define CC   10
#define DOUT 64
#define SEQn 512
#define BB   32
#define SI   100
#define NSL  32     // dim slices (10 dims each)
#define NGR  8      // batch groups
#define BPG  4      // batches per group
#define NTH  640
#define DPS  10
#define RPS  100    // flat S-rows per slice

// sync layout (ints): per group g: 8 barrier counters at ws[g*128 + l*16];
// 4 col flags at ws[1024 + g*64 + f*16]
#define CFBASE 1024
// pubA entry (floats): uf[40] za[128] zo[256] pad -> 448
#define PSA   448
#define UF_O  0
#define ZA_O  40
#define ZO_O  168
#define HALF_A (NGR*NSL*PSA)
#define PSB   320   // pubB entry: col[320]
#define PUBA_OFF 2048
#define PUBB_OFF (PUBA_OFF + 2*HALF_A)

typedef float f4 __attribute__((ext_vector_type(4)));

__device__ __forceinline__ void llc_ld(f4* dst, const float* p) {
    f4 r;
    asm volatile("global_load_dwordx4 %0, %1, off sc0 sc1" : "=&v"(r) : "v"(p));
    asm volatile("s_waitcnt vmcnt(0)" ::: "memory");
    __builtin_amdgcn_sched_barrier(0);
    *dst = r;
}
__device__ __forceinline__ void llc_st(float* p, f4 v) {
    asm volatile("global_store_dwordx4 %0, %1, off sc0 sc1" :: "v"(p), "v"(v) : "memory");
}

__global__ void prep_kernel(int* ctr) {
    int i = blockIdx.x * blockDim.x + threadIdx.x;
    if (i < 2048) ctr[i] = 0;
}

// 32-peer barrier with arrival spread over 8 cache lines and 8-lane wave poll.
__device__ __forceinline__ void gbar8(int* base, int slice, int target) {
    asm volatile("s_waitcnt vmcnt(0)" ::: "memory");
    __syncthreads();
    if (threadIdx.x == 0)
        __hip_atomic_fetch_add(&base[(slice & 7) * 16], 1, __ATOMIC_RELEASE, __HIP_MEMORY_SCOPE_AGENT);
    if (threadIdx.x < 8) {
        for (;;) {
            int v = __hip_atomic_load(&base[threadIdx.x * 16], __ATOMIC_RELAXED, __HIP_MEMORY_SCOPE_AGENT);
            v += __shfl_xor(v, 1, 8);
            v += __shfl_xor(v, 2, 8);
            v += __shfl_xor(v, 4, 8);
            if (v >= target) break;
            __builtin_amdgcn_s_sleep(2);
        }
    }
    __syncthreads();
}

__global__ __launch_bounds__(NTH) void recur_kernel(
    const int* __restrict__ sentence, const int* __restrict__ speaker,
    const float* __restrict__ LutP, const float* __restrict__ LutS,
    const float* __restrict__ NaW,  const float* __restrict__ NaB,
    const float* __restrict__ NuW,  const float* __restrict__ NuB,
    const float* __restrict__ NoW,  const float* __restrict__ NoB,
    const float* __restrict__ FuW,  const float* __restrict__ FuB,
    const float* __restrict__ FoW,  const float* __restrict__ FoB,
    float* __restrict__ ws, const int* __restrict__ Tptr,
    float* __restrict__ out)
{
    const int tid  = threadIdx.x;
    const int s    = blockIdx.x & (NSL - 1);
    const int g    = blockIdx.x >> 5;
    const bool owner = (s < BPG);           // slice j owns batch g*4+j
    const int dbase = s * DPS;
    const int rbase = s * RPS;
    int*  ctr  = (int*)ws + g * 128;                 // 8 words, stride 16
    int*  CFg  = (int*)ws + CFBASE + g * 64;         // 4 words, stride 16
    float* pubA = ws + PUBA_OFF;
    float* pubB = ws + PUBB_OFF;

    const int c_   = tid >> 6;   // wave id = owned u-column 0..9
    const int lane = tid & 63;

    __shared__ float xsE[BPG][3328];     // state: 64 rgrp x 52 (50 used)
    __shared__ float wNa[RPS][32];
    __shared__ float wNo[RPS][65];
    __shared__ float naT0[DPS][32];
    __shared__ float noT0[DPS][65];
    __shared__ float identsh[BPG][DP];
    __shared__ float ufull[BPG][DD];
    __shared__ float colL[BPG][DD];
    __shared__ float ucol[BPG*DPS];      // final u for own dims (flat 40)
    __shared__ float zr[BPG*32];
    __shared__ float zor[BPG*DOUT];
    __shared__ float zastage[NSL][32];
    __shared__ float zostage[NSL][DOUT];
    __shared__ float fos[BPG][RPS];
    __shared__ float nubO[DPS];
    __shared__ float nabL[32];
    __shared__ float aoutL[32];
    __shared__ float muL[CC], sgL[CC], ggL[CC];
    __shared__ float alphaL[SEQn];
    __shared__ float histL[SI];
    __shared__ float idtF[DP];
    __shared__ float colF[DD];
    __shared__ float o_own[DOUT];
    __shared__ float foNoL[DOUT];
    __shared__ int   sentL[SEQn];
    __shared__ int   posidx[SEQn];
    __shared__ int   vstart[SI + 1];
    __shared__ int   vcnt[SI];

    // ---------------- prologue: stage weights ----------------
    for (int i = tid; i < RPS * 30; i += NTH) {
        int r = i / 30, c = i % 30;
        wNa[r][c] = NaW[(rbase + r) * 30 + c];
    }
    for (int i = tid; i < RPS * 64; i += NTH) {
        int r = i / 64, o = i % 64;
        wNo[r][o] = NoW[(rbase + r) * 64 + o];
    }
    if (tid < DPS * 30) { int dl = tid / 30, c = tid % 30; naT0[dl][c] = NaW[((dbase + dl) * KK) * 30 + c]; }
    if (tid < DPS * 64) { int dl = tid >> 6, o = tid & 63; noT0[dl][o] = NoW[((dbase + dl) * KK) * 64 + o]; }
    if (tid < DPS) nubO[tid] = NuB[dbase + tid];
    if (tid >= 16 && tid < 48) { int c = tid - 16; nabL[c] = (c < 30) ? NaB[c] : 0.f; }
    for (int i = tid; i < BPG * DP; i += NTH) {
        int j = i / DP, v = i % DP;
        identsh[j][v] = LutS[speaker[g * BPG + j] * DP + v];
    }
    __syncthreads();

    // Nu column weights into registers: thread (c_, lane) holds rows lane*50..+49, col dbase+c_
    float w[50];
    #pragma unroll
    for (int q = 0; q < 50; ++q)
        w[q] = NuW[(size_t)(lane * 50 + q) * DD + dbase + c_];

    // fo rows for this slice (per batch)
    for (int i = tid; i < BPG * RPS; i += NTH) {
        int j = i / RPS, r = i % RPS;
        float acc = FoB[rbase + r];
        for (int v = 0; v < DP; v += 8) {
            float wv[8];
            #pragma unroll
            for (int e = 0; e < 8; ++e) wv[e] = FoW[(v + e) * 3200 + rbase + r];
            #pragma unroll
            for (int e = 0; e < 8; ++e) acc += identsh[j][v + e] * wv[e];
        }
        fos[j][r] = acc;
    }
    if (owner) {
        if (tid < DP) {
            float acc = FuB[tid];
            for (int v = 0; v < DP; v += 8) {
                float wv[8];
                #pragma unroll
                for (int e = 0; e < 8; ++e) wv[e] = FuW[(v + e) * DP + tid];
                #pragma unroll
                for (int e = 0; e < 8; ++e) acc += identsh[s][v + e] * wv[e];
            }
            idtF[tid] = tanhf(acc);
        }
        if (tid >= 512 && tid < 512 + CC) muL[tid - 512] = 0.f;
        if (tid < SEQn) sentL[tid] = sentence[(g * BPG + s) * SEQn + tid];
        __syncthreads();
        // bucket positions by vocab (deterministic ascending order)
        if (tid < SI) { int cnt = 0; for (int q = 0; q < SEQn; ++q) if (sentL[q] == tid) ++cnt; vcnt[tid] = cnt; }
        __syncthreads();
        if (tid == 0) { int run = 0; for (int v = 0; v < SI; ++v) { vstart[v] = run; run += vcnt[v]; } vstart[SI] = run; }
        __syncthreads();
        if (tid < SI) { int k = vstart[tid]; for (int q = 0; q < SEQn; ++q) if (sentL[q] == tid) posidx[k++] = q; }
    }
    // S0: every tap = [ident ; 0]
    for (int i = tid; i < BPG * 3200; i += NTH) {
        int j = i / 3200, row = i % 3200;
        int d = row / KK;
        xsE[j][(row / 50) * 52 + (row % 50)] = (d < DP) ? identsh[j][d] : 0.f;
    }
    __syncthreads();
    // za0 (all 100 rows, tap0 = real ident) and foNo parts
    if (tid < 128) {
        int j = tid >> 5, c = tid & 31;
        float acc = 0.f;
        if (c < 30)
            for (int rr = 0; rr < RPS; ++rr) {
                int row = rbase + rr;
                acc += xsE[j][(row / 50) * 52 + (row % 50)] * wNa[rr][c];
            }
        zr[j * 32 + c] = acc;
    }
    if (tid >= 128 && tid < 384) {
        int t = tid - 128, j = t >> 6, o = t & 63;
        float acc = 0.f;
        for (int rr = 0; rr < RPS; ++rr) acc += fos[j][rr] * wNo[rr][o];
        zor[j * 64 + o] = acc;
    }
    __syncthreads();
    {
        float* pa0 = pubA + (size_t)(g * NSL + s) * PSA;   // half 0
        if (tid < 32) llc_st(pa0 + ZA_O + tid * 4, *(f4*)&zr[tid * 4]);
        if (tid >= 32 && tid < 96) { int q = tid - 32; llc_st(pa0 + ZO_O + q * 4, *(f4*)&zor[q * 4]); }
    }
    gbar8(ctr, s, 32 * 1);

    const int T = Tptr[0];

    for (int i = 0; i < T; ++i) {
        const int rh = i & 1, wh = rh ^ 1;
        float* pa_r = pubA + (size_t)rh * HALF_A + (size_t)g * NSL * PSA;
        float* pa_w = pubA + (size_t)wh * HALF_A + (size_t)(g * NSL + s) * PSA;

        // ---- P1: ONE batched LLC read: uf (all blocks) + za/zo (owners) ----
        {
            f4 v_uf = {0,0,0,0}, v_za = {0,0,0,0}, v_zo = {0,0,0,0};
            const bool h_uf = (i > 0 && tid < 320);
            const bool h_za = (owner && tid >= 320 && tid < 576);
            const bool h_zo = (owner && tid < 512);
            if (h_uf) {
                const float* p = pa_r + (tid / 10) * PSA + UF_O + (tid % 10) * 4;
                asm volatile("global_load_dwordx4 %0, %1, off sc0 sc1" : "=&v"(v_uf) : "v"(p));
            }
            if (h_za) {
                int t = tid - 320;
                const float* p = pa_r + (t >> 3) * PSA + ZA_O + s * 32 + (t & 7) * 4;
                asm volatile("global_load_dwordx4 %0, %1, off sc0 sc1" : "=&v"(v_za) : "v"(p));
            }
            if (h_zo) {
                const float* p = pa_r + (tid >> 4) * PSA + ZO_O + s * 64 + (tid & 15) * 4;
                asm volatile("global_load_dwordx4 %0, %1, off sc0 sc1" : "=&v"(v_zo) : "v"(p));
            }
            asm volatile("s_waitcnt vmcnt(0)" ::: "memory");
            __builtin_amdgcn_sched_barrier(0);
            if (h_uf) {
                int p = tid / 10, q = tid % 10;
                #pragma unroll
                for (int e = 0; e < 4; ++e) { int f = q * 4 + e; ufull[f / 10][p * 10 + (f % 10)] = v_uf[e]; }
            }
            if (h_za) { int t = tid - 320; *(f4*)&zastage[t >> 3][(t & 7) * 4] = v_za; }
            if (h_zo) { *(f4*)&zostage[tid >> 4][(tid & 15) * 4] = v_zo; }
        }
        __syncthreads();

        // ---- owner: serial chain for its batch ----
        if (owner) {
            if (tid < 30) {
                float a = nabL[tid];
                for (int p = 0; p < NSL; ++p) a += zastage[p][tid];
                aoutL[tid] = a;
            }
            if (tid >= 64 && tid < 128) {
                int o = tid - 64;
                float v = 0.f;
                for (int p = 0; p < NSL; ++p) v += zostage[p][o];
                if (i == 0) { foNoL[o] = NoB[o] + v; o_own[o] = 0.f; }
                else        o_own[o] = foNoL[o] + v;
            }
            __syncthreads();
            if (tid < CC) {
                muL[tid] += 0.05f * expf(aoutL[tid]);
                sgL[tid] = expf(aoutL[10 + tid]);
                float m = -1e30f;
                for (int q = 0; q < CC; ++q) m = fmaxf(m, aoutL[20 + q]);
                float ssum = 0.f;
                for (int q = 0; q < CC; ++q) ssum += expf(aoutL[20 + q] - m);
                ggL[tid] = expf(aoutL[20 + tid] - m) / ssum;
            }
            __syncthreads();
            if (tid < SEQn) {
                float J = (float)(tid + 1);
                float a = 0.f;
                #pragma unroll
                for (int c = 0; c < CC; ++c) { float dm = muL[c] - J; a += ggL[c] * __expf(-0.5f * sgL[c] * dm * dm); }
                alphaL[tid] = a * 0.3989422917366028f;
            }
            __syncthreads();
            if (tid < SI) {
                float h = 0.f;
                for (int k = vstart[tid]; k < vstart[tid + 1]; ++k) h += alphaL[posidx[k]];
                histL[tid] = h;
            }
            __syncthreads();
            if (tid < DP) {
                float acc = idtF[tid];
                for (int v = 0; v < SI; v += 10) {
                    float wv[10];
                    #pragma unroll
                    for (int e = 0; e < 10; ++e) wv[e] = LutP[(v + e) * DP + tid];
                    #pragma unroll
                    for (int e = 0; e < 10; ++e) acc += histL[v + e] * wv[e];
                }
                colF[tid] = acc;
            } else if (tid < DD) {
                colF[tid] = o_own[tid - DP] * (1.0f / 30.0f);
            }
            __syncthreads();
            if (i > 0 && tid < DOUT)
                out[((size_t)(i - 1) * BB + (g * BPG + s)) * DOUT + tid] = o_own[tid];
            if (tid < 80) llc_st(pubB + (size_t)(g * BPG + s) * PSB + tid * 4, *(f4*)&colF[tid * 4]);
            // drain col stores, then raise flag
            asm volatile("s_waitcnt vmcnt(0)" ::: "memory");
            __syncthreads();
            if (tid == 0)
                __hip_atomic_store(&CFg[s * 16], i + 1, __ATOMIC_RELEASE, __HIP_MEMORY_SCOPE_AGENT);
        }

        // ---- shift (all blocks): tap1 <- u_{i-1}; taps 2..9 <- old 1..8 ----
        for (int it = tid; it < BPG * DD; it += NTH) {
            int j = it / DD, d = it % DD;
            float* p = &xsE[j][(d / 5) * 52 + (d % 5) * 10];
            float t0 = p[0];
            float v1 = p[1], v2 = p[2], v3 = p[3], v4 = p[4], v5 = p[5], v6 = p[6], v7 = p[7], v8 = p[8];
            p[1] = (i == 0) ? t0 : ufull[j][d];
            p[2] = v1; p[3] = v2; p[4] = v3; p[5] = v4; p[6] = v5; p[7] = v6; p[8] = v7; p[9] = v8;
        }
        // ---- col-flag wait (4 separate lines) ----
        if (tid < BPG) {
            while (__hip_atomic_load(&CFg[tid * 16], __ATOMIC_RELAXED, __HIP_MEMORY_SCOPE_AGENT) < i + 1)
                __builtin_amdgcn_s_sleep(2);
        }
        __syncthreads();

        // ---- P3: read C-columns, insert tap0 ----
        if (tid < 320) {
            int j = tid / 80, q = tid % 80;
            f4 v; llc_ld(&v, pubB + (size_t)(g * BPG + j) * PSB + q * 4);
            #pragma unroll
            for (int e = 0; e < 4; ++e) colL[j][q * 4 + e] = v[e];
        }
        __syncthreads();
        for (int it = tid; it < BPG * DD; it += NTH) {
            int j = it / DD, d = it % DD;
            xsE[j][(d / 5) * 52 + (d % 5) * 10] = colL[j][d];
        }
        __syncthreads();

        // ---- E: final u for own 10 dims (weights in regs) ----
        {
            float accE[BPG];
            #pragma unroll
            for (int j = 0; j < BPG; ++j) {
                const float* xb = &xsE[j][lane * 52];
                float a = 0.f;
                #pragma unroll
                for (int qq = 0; qq < 12; ++qq) {
                    f4 x = *(const f4*)(xb + qq * 4);
                    a += x.x * w[qq * 4] + x.y * w[qq * 4 + 1] + x.z * w[qq * 4 + 2] + x.w * w[qq * 4 + 3];
                }
                a += xb[48] * w[48] + xb[49] * w[49];
                accE[j] = a;
            }
            #pragma unroll
            for (int j = 0; j < BPG; ++j)
                for (int off = 32; off; off >>= 1) accE[j] += __shfl_xor(accE[j], off, 64);
            if (lane == 0) {
                #pragma unroll
                for (int j = 0; j < BPG; ++j) ucol[j * DPS + c_] = accE[j] + nubO[c_];
            }
        }
        __syncthreads();
        // ---- publish uf EARLY (drain overlaps za/zo compute) ----
        if (tid < 10) llc_st(pa_w + UF_O + tid * 4, *(f4*)&ucol[tid * 4]);

        // ---- za/zo partials for next step: k>=1 rows + own-final-u tap0 fold ----
        if (tid < 128) {
            int j = tid >> 5, c = tid & 31;
            float acc = 0.f;
            if (c < 30) {
                for (int dd = 0; dd < DPS; ++dd) {
                    int rg = 2 * s + (dd >= 5);
                    int of = dd * 10 - (dd >= 5 ? 50 : 0);
                    const float* xb = &xsE[j][rg * 52 + of];
                    #pragma unroll
                    for (int k = 1; k < KK; ++k) acc += xb[k] * wNa[dd * 10 + k][c];
                }
                #pragma unroll
                for (int dl = 0; dl < DPS; ++dl) acc += ucol[j * DPS + dl] * naT0[dl][c];
            }
            zr[j * 32 + c] = acc;
        }
        if (tid >= 128 && tid < 384) {
            int t = tid - 128, j = t >> 6, o = t & 63;
            float acc = 0.f;
            for (int dd = 0; dd < DPS; ++dd) {
                int rg = 2 * s + (dd >= 5);
                int of = dd * 10 - (dd >= 5 ? 50 : 0);
                const float* xb = &xsE[j][rg * 52 + of];
                #pragma unroll
                for (int k = 1; k < KK; ++k) acc += xb[k] * wNo[dd * 10 + k][o];
            }
            #pragma unroll
            for (int dl = 0; dl < DPS; ++dl) acc += ucol[j * DPS + dl] * noT0[dl][o];
            zor[j * 64 + o] = acc;
        }
        __syncthreads();

        // ---- publish za / zo, barrier (barA) ----
        if (tid >= 10 && tid < 42)  { int q = tid - 10; llc_st(pa_w + ZA_O + q * 4, *(f4*)&zr[q * 4]); }
        if (tid >= 42 && tid < 106) { int q = tid - 42; llc_st(pa_w + ZO_O + q * 4, *(f4*)&zor[q * 4]); }
        gbar8(ctr, s, 32 * (i + 2));
    }

    // ---- final output o_{T-1} (owner) ----
    if (owner) {
        const float* pa_r = pubA + (size_t)(T & 1) * HALF_A + (size_t)g * NSL * PSA;
        if (tid < 512) {
            f4 v; llc_ld(&v, pa_r + (tid >> 4) * PSA + ZO_O + s * 64 + (tid & 15) * 4);
            *(f4*)&zostage[tid >> 4][(tid & 15) * 4] = v;
        }
        __syncthreads();
        if (tid < DOUT) {
            float v = foNoL[tid];
            for (int p = 0; p < NSL; ++p) v += zostage[p][tid];
            out[((size_t)(T - 1) * BB + (g * BPG + s)) * DOUT + tid] = v;
        }
    }
}

extern "C" void kernel_launch(void* const* d_in, const int* in_sizes, int n_in,
                              void* d_out, int out_size, void* d_ws, size_t ws_size,
                              hipStream_t stream) {
    const int*   sentence = (const int*)d_in[0];
    const int*   speaker  = (const int*)d_in[1];
    const float* LutP = (const float*)d_in[2];
    const float* LutS = (const float*)d_in[3];
    const float* NaW  = (const float*)d_in[4];
    const float* NaB  = (const float*)d_in[5];
    const float* NuW  = (const float*)d_in[6];
    const float* NuB  = (const float*)d_in[7];
    const float* NoW  = (const float*)d_in[8];
    const float* NoB  = (const float*)d_in[9];
    const float* FuW  = (const float*)d_in[10];
    const float* FuB  = (const float*)d_in[11];
    const float* FoW  = (const float*)d_in[12];
    const float* FoB  = (const float*)d_in[13];
    const int*   Tptr = (const int*)d_in[14];
    float* ws   = (float*)d_ws;
    float* outp = (float*)d_out;

    hipLaunchKernelGGL(prep_kernel, dim3(2), dim3(1024), 0, stream, (int*)d_ws);
    hipLaunchKernelGGL(recur_kernel, dim3(NSL * NGR), dim3(NTH), 0, stream,
                       sentence, speaker, LutP, LutS, NaW, NaB,
                       NuW, NuB, NoW, NoB, FuW, FuB, FoW, FoB,
                       ws, Tptr, outp);
}

// Round 19
// 4597.705 us; speedup vs baseline: 2.1516x; 1.0167x over previous
//
#include <hip/hip_runtime.h>

#define DP   256
#define DD   320
#define KK   10
#define CC   10
#define DOUT 64
#define SEQn 512
#define BB   32
#define SI   100
#define NSL  32     // dim slices (10 dims each)
#define NGR  8      // batch groups
#define BPG  4      // batches per group
#define NTH  640
#define DPS  10
#define RPS  100    // flat S-rows per slice

// sync layout (ints): per group g: 8 barrier counters at ws[g*128 + l*16];
// 4 col flags at ws[1024 + g*64 + f*16]
#define CFBASE 1024
// pubA entry (floats): uf[40] za[128] zo[256] pad -> 448
#define PSA   448
#define UF_O  0
#define ZA_O  40
#define ZO_O  168
#define HALF_A (NGR*NSL*PSA)
#define PSB   320   // pubB entry: col[320]
#define PUBA_OFF 2048
#define PUBB_OFF (PUBA_OFF + 2*HALF_A)

typedef float f4 __attribute__((ext_vector_type(4)));

__device__ __forceinline__ void llc_ld(f4* dst, const float* p) {
    f4 r;
    asm volatile("global_load_dwordx4 %0, %1, off sc0 sc1" : "=&v"(r) : "v"(p));
    asm volatile("s_waitcnt vmcnt(0)" ::: "memory");
    __builtin_amdgcn_sched_barrier(0);
    *dst = r;
}
__device__ __forceinline__ void llc_st(float* p, f4 v) {
    asm volatile("global_store_dwordx4 %0, %1, off sc0 sc1" :: "v"(p), "v"(v) : "memory");
}

__global__ void prep_kernel(int* ctr) {
    int i = blockIdx.x * blockDim.x + threadIdx.x;
    if (i < 2048) ctr[i] = 0;
}

// 32-peer barrier with arrival spread over 8 cache lines and 8-lane wave poll.
__device__ __forceinline__ void gbar8(int* base, int slice, int target) {
    asm volatile("s_waitcnt vmcnt(0)" ::: "memory");
    __syncthreads();
    if (threadIdx.x == 0)
        __hip_atomic_fetch_add(&base[(slice & 7) * 16], 1, __ATOMIC_RELEASE, __HIP_MEMORY_SCOPE_AGENT);
    if (threadIdx.x < 8) {
        for (;;) {
            int v = __hip_atomic_load(&base[threadIdx.x * 16], __ATOMIC_RELAXED, __HIP_MEMORY_SCOPE_AGENT);
            v += __shfl_xor(v, 1, 8);
            v += __shfl_xor(v, 2, 8);
            v += __shfl_xor(v, 4, 8);
            if (v >= target) break;
            __builtin_amdgcn_s_sleep(2);
        }
    }
    __syncthreads();
}

__global__ __launch_bounds__(NTH) void recur_kernel(
    const int* __restrict__ sentence, const int* __restrict__ speaker,
    const float* __restrict__ LutP, const float* __restrict__ LutS,
    const float* __restrict__ NaW,  const float* __restrict__ NaB,
    const float* __restrict__ NuW,  const float* __restrict__ NuB,
    const float* __restrict__ NoW,  const float* __restrict__ NoB,
    const float* __restrict__ FuW,  const float* __restrict__ FuB,
    const float* __restrict__ FoW,  const float* __restrict__ FoB,
    float* __restrict__ ws, const int* __restrict__ Tptr,
    float* __restrict__ out)
{
    const int tid  = threadIdx.x;
    const int s    = blockIdx.x & (NSL - 1);
    const int g    = blockIdx.x >> 5;
    const bool owner = (s < BPG);           // slice j owns batch g*4+j
    const int dbase = s * DPS;
    const int rbase = s * RPS;
    int*  ctr  = (int*)ws + g * 128;                 // 8 words, stride 16
    int*  CFg  = (int*)ws + CFBASE + g * 64;         // 4 words, stride 16
    float* pubA = ws + PUBA_OFF;
    float* pubB = ws + PUBB_OFF;

    const int c_   = tid >> 6;   // wave id = owned u-column 0..9
    const int lane = tid & 63;

    __shared__ float xsE[BPG][3328];     // state: 64 rgrp x 52 (50 used)
    __shared__ float wNa[RPS][32];
    __shared__ float wNo[RPS][65];
    __shared__ float naT0[DPS][32];
    __shared__ float noT0[DPS][65];
    __shared__ float identsh[BPG][DP];
    __shared__ float ufull[BPG][DD];
    __shared__ float colL[BPG][DD];
    __shared__ float ucol[BPG*DPS];      // final u for own dims (flat 40)
    __shared__ float zr[BPG*32];
    __shared__ float zor[BPG*DOUT];
    __shared__ float zastage[NSL][32];
    __shared__ float zostage[NSL][DOUT];
    __shared__ float fos[BPG][RPS];
    __shared__ float nubO[DPS];
    __shared__ float nabL[32];
    __shared__ float aoutL[32];
    __shared__ float muL[CC], sgL[CC], ggL[CC];
    __shared__ float alphaL[SEQn];
    __shared__ float histL[SI];
    __shared__ float idtF[DP];
    __shared__ float colF[DD];
    __shared__ float o_own[DOUT];
    __shared__ float foNoL[DOUT];
    __shared__ int   sentL[SEQn];
    __shared__ int   posidx[SEQn];
    __shared__ int   vstart[SI + 1];
    __shared__ int   vcnt[SI];

    // ---------------- prologue: stage weights ----------------
    for (int i = tid; i < RPS * 30; i += NTH) {
        int r = i / 30, c = i % 30;
        wNa[r][c] = NaW[(rbase + r) * 30 + c];
    }
    for (int i = tid; i < RPS * 64; i += NTH) {
        int r = i / 64, o = i % 64;
        wNo[r][o] = NoW[(rbase + r) * 64 + o];
    }
    if (tid < DPS * 30) { int dl = tid / 30, c = tid % 30; naT0[dl][c] = NaW[((dbase + dl) * KK) * 30 + c]; }
    if (tid < DPS * 64) { int dl = tid >> 6, o = tid & 63; noT0[dl][o] = NoW[((dbase + dl) * KK) * 64 + o]; }
    if (tid < DPS) nubO[tid] = NuB[dbase + tid];
    if (tid >= 16 && tid < 48) { int c = tid - 16; nabL[c] = (c < 30) ? NaB[c] : 0.f; }
    for (int i = tid; i < BPG * DP; i += NTH) {
        int j = i / DP, v = i % DP;
        identsh[j][v] = LutS[speaker[g * BPG + j] * DP + v];
    }
    __syncthreads();

    // Nu column weights into registers: thread (c_, lane) holds rows lane*50..+49, col dbase+c_
    float w[50];
    #pragma unroll
    for (int q = 0; q < 50; ++q)
        w[q] = NuW[(size_t)(lane * 50 + q) * DD + dbase + c_];

    // fo rows for this slice (per batch)
    for (int i = tid; i < BPG * RPS; i += NTH) {
        int j = i / RPS, r = i % RPS;
        float acc = FoB[rbase + r];
        for (int v = 0; v < DP; v += 8) {
            float wv[8];
            #pragma unroll
            for (int e = 0; e < 8; ++e) wv[e] = FoW[(v + e) * 3200 + rbase + r];
            #pragma unroll
            for (int e = 0; e < 8; ++e) acc += identsh[j][v + e] * wv[e];
        }
        fos[j][r] = acc;
    }
    if (owner) {
        if (tid < DP) {
            float acc = FuB[tid];
            for (int v = 0; v < DP; v += 8) {
                float wv[8];
                #pragma unroll
                for (int e = 0; e < 8; ++e) wv[e] = FuW[(v + e) * DP + tid];
                #pragma unroll
                for (int e = 0; e < 8; ++e) acc += identsh[s][v + e] * wv[e];
            }
            idtF[tid] = tanhf(acc);
        }
        if (tid >= 512 && tid < 512 + CC) muL[tid - 512] = 0.f;
        if (tid < SEQn) sentL[tid] = sentence[(g * BPG + s) * SEQn + tid];
        __syncthreads();
        // bucket positions by vocab (deterministic ascending order)
        if (tid < SI) { int cnt = 0; for (int q = 0; q < SEQn; ++q) if (sentL[q] == tid) ++cnt; vcnt[tid] = cnt; }
        __syncthreads();
        if (tid == 0) { int run = 0; for (int v = 0; v < SI; ++v) { vstart[v] = run; run += vcnt[v]; } vstart[SI] = run; }
        __syncthreads();
        if (tid < SI) { int k = vstart[tid]; for (int q = 0; q < SEQn; ++q) if (sentL[q] == tid) posidx[k++] = q; }
    }
    // S0: every tap = [ident ; 0]
    for (int i = tid; i < BPG * 3200; i += NTH) {
        int j = i / 3200, row = i % 3200;
        int d = row / KK;
        xsE[j][(row / 50) * 52 + (row % 50)] = (d < DP) ? identsh[j][d] : 0.f;
    }
    __syncthreads();
    // za0 (all 100 rows, tap0 = real ident) and foNo parts
    if (tid < 128) {
        int j = tid >> 5, c = tid & 31;
        float acc = 0.f;
        if (c < 30)
            for (int rr = 0; rr < RPS; ++rr) {
                int row = rbase + rr;
                acc += xsE[j][(row / 50) * 52 + (row % 50)] * wNa[rr][c];
            }
        zr[j * 32 + c] = acc;
    }
    if (tid >= 128 && tid < 384) {
        int t = tid - 128, j = t >> 6, o = t & 63;
        float acc = 0.f;
        for (int rr = 0; rr < RPS; ++rr) acc += fos[j][rr] * wNo[rr][o];
        zor[j * 64 + o] = acc;
    }
    __syncthreads();
    {
        float* pa0 = pubA + (size_t)(g * NSL + s) * PSA;   // half 0
        if (tid < 32) llc_st(pa0 + ZA_O + tid * 4, *(f4*)&zr[tid * 4]);
        if (tid >= 32 && tid < 96) { int q = tid - 32; llc_st(pa0 + ZO_O + q * 4, *(f4*)&zor[q * 4]); }
    }
    gbar8(ctr, s, 32 * 1);

    const int T = Tptr[0];

    for (int i = 0; i < T; ++i) {
        const int rh = i & 1, wh = rh ^ 1;
        float* pa_r = pubA + (size_t)rh * HALF_A + (size_t)g * NSL * PSA;
        float* pa_w = pubA + (size_t)wh * HALF_A + (size_t)(g * NSL + s) * PSA;

        // ---- P1: ONE batched LLC read: uf (all blocks) + za/zo (owners) ----
        {
            f4 v_uf = {0,0,0,0}, v_za = {0,0,0,0}, v_zo = {0,0,0,0};
            const bool h_uf = (i > 0 && tid < 320);
            const bool h_za = (owner && tid >= 320 && tid < 576);
            const bool h_zo = (owner && tid < 512);
            if (h_uf) {
                const float* p = pa_r + (tid / 10) * PSA + UF_O + (tid % 10) * 4;
                asm volatile("global_load_dwordx4 %0, %1, off sc0 sc1" : "=&v"(v_uf) : "v"(p));
            }
            if (h_za) {
                int t = tid - 320;
                const float* p = pa_r + (t >> 3) * PSA + ZA_O + s * 32 + (t & 7) * 4;
                asm volatile("global_load_dwordx4 %0, %1, off sc0 sc1" : "=&v"(v_za) : "v"(p));
            }
            if (h_zo) {
                const float* p = pa_r + (tid >> 4) * PSA + ZO_O + s * 64 + (tid & 15) * 4;
                asm volatile("global_load_dwordx4 %0, %1, off sc0 sc1" : "=&v"(v_zo) : "v"(p));
            }
            asm volatile("s_waitcnt vmcnt(0)" ::: "memory");
            __builtin_amdgcn_sched_barrier(0);
            if (h_uf) {
                int p = tid / 10, q = tid % 10;
                #pragma unroll
                for (int e = 0; e < 4; ++e) { int f = q * 4 + e; ufull[f / 10][p * 10 + (f % 10)] = v_uf[e]; }
            }
            if (h_za) { int t = tid - 320; *(f4*)&zastage[t >> 3][(t & 7) * 4] = v_za; }
            if (h_zo) { *(f4*)&zostage[tid >> 4][(tid & 15) * 4] = v_zo; }
        }
        __syncthreads();

        // ---- owner: serial chain for its batch ----
        if (owner) {
            if (tid < 30) {
                float a = nabL[tid];
                for (int p = 0; p < NSL; ++p) a += zastage[p][tid];
                aoutL[tid] = a;
            }
            if (tid >= 64 && tid < 128) {
                int o = tid - 64;
                float v = 0.f;
                for (int p = 0; p < NSL; ++p) v += zostage[p][o];
                if (i == 0) { foNoL[o] = NoB[o] + v; o_own[o] = 0.f; }
                else        o_own[o] = foNoL[o] + v;
            }
            __syncthreads();
            if (tid < CC) {
                muL[tid] += 0.05f * expf(aoutL[tid]);
                sgL[tid] = expf(aoutL[10 + tid]);
                float m = -1e30f;
                for (int q = 0; q < CC; ++q) m = fmaxf(m, aoutL[20 + q]);
                float ssum = 0.f;
                for (int q = 0; q < CC; ++q) ssum += expf(aoutL[20 + q] - m);
                ggL[tid] = expf(aoutL[20 + tid] - m) / ssum;
            }
            __syncthreads();
            if (tid < SEQn) {
                float J = (float)(tid + 1);
                float a = 0.f;
                #pragma unroll
                for (int c = 0; c < CC; ++c) { float dm = muL[c] - J; a += ggL[c] * __expf(-0.5f * sgL[c] * dm * dm); }
                alphaL[tid] = a * 0.3989422917366028f;
            }
            __syncthreads();
            if (tid < SI) {
                float h = 0.f;
                for (int k = vstart[tid]; k < vstart[tid + 1]; ++k) h += alphaL[posidx[k]];
                histL[tid] = h;
            }
            __syncthreads();
            if (tid < DP) {
                float acc = idtF[tid];
                for (int v = 0; v < SI; v += 10) {
                    float wv[10];
                    #pragma unroll
                    for (int e = 0; e < 10; ++e) wv[e] = LutP[(v + e) * DP + tid];
                    #pragma unroll
                    for (int e = 0; e < 10; ++e) acc += histL[v + e] * wv[e];
                }
                colF[tid] = acc;
            } else if (tid < DD) {
                colF[tid] = o_own[tid - DP] * (1.0f / 30.0f);
            }
            __syncthreads();
            // wave 0 alone publishes col (all 80 chunks), drains, raises flag.
            if (tid < 64) {
                float* pb = pubB + (size_t)(g * BPG + s) * PSB;
                for (int q = tid; q < 80; q += 64) llc_st(pb + q * 4, *(f4*)&colF[q * 4]);
                asm volatile("s_waitcnt vmcnt(0)" ::: "memory");
                if (tid == 0)
                    __hip_atomic_store(&CFg[s * 16], i + 1, __ATOMIC_RELEASE, __HIP_MEMORY_SCOPE_AGENT);
            }
            // out write moved OFF the critical drain window (wave 1; drained at gbar)
            if (i > 0 && tid >= 64 && tid < 128)
                out[((size_t)(i - 1) * BB + (g * BPG + s)) * DOUT + (tid - 64)] = o_own[tid - 64];
        }

        // ---- shift (all blocks): tap1 <- u_{i-1}; taps 2..9 <- old 1..8 ----
        for (int it = tid; it < BPG * DD; it += NTH) {
            int j = it / DD, d = it % DD;
            float* p = &xsE[j][(d / 5) * 52 + (d % 5) * 10];
            float t0 = p[0];
            float v1 = p[1], v2 = p[2], v3 = p[3], v4 = p[4], v5 = p[5], v6 = p[6], v7 = p[7], v8 = p[8];
            p[1] = (i == 0) ? t0 : ufull[j][d];
            p[2] = v1; p[3] = v2; p[4] = v3; p[5] = v4; p[6] = v5; p[7] = v6; p[8] = v7; p[9] = v8;
        }
        // ---- col-flag wait (4 separate lines) ----
        if (tid < BPG) {
            while (__hip_atomic_load(&CFg[tid * 16], __ATOMIC_RELAXED, __HIP_MEMORY_SCOPE_AGENT) < i + 1)
                __builtin_amdgcn_s_sleep(2);
        }
        __syncthreads();

        // ---- P3: read C-columns, insert tap0 ----
        if (tid < 320) {
            int j = tid / 80, q = tid % 80;
            f4 v; llc_ld(&v, pubB + (size_t)(g * BPG + j) * PSB + q * 4);
            #pragma unroll
            for (int e = 0; e < 4; ++e) colL[j][q * 4 + e] = v[e];
        }
        __syncthreads();
        for (int it = tid; it < BPG * DD; it += NTH) {
            int j = it / DD, d = it % DD;
            xsE[j][(d / 5) * 52 + (d % 5) * 10] = colL[j][d];
        }
        __syncthreads();

        // ---- E: final u for own 10 dims (weights in regs) ----
        {
            float accE[BPG];
            #pragma unroll
            for (int j = 0; j < BPG; ++j) {
                const float* xb = &xsE[j][lane * 52];
                float a = 0.f;
                #pragma unroll
                for (int qq = 0; qq < 12; ++qq) {
                    f4 x = *(const f4*)(xb + qq * 4);
                    a += x.x * w[qq * 4] + x.y * w[qq * 4 + 1] + x.z * w[qq * 4 + 2] + x.w * w[qq * 4 + 3];
                }
                a += xb[48] * w[48] + xb[49] * w[49];
                accE[j] = a;
            }
            #pragma unroll
            for (int j = 0; j < BPG; ++j)
                for (int off = 32; off; off >>= 1) accE[j] += __shfl_xor(accE[j], off, 64);
            if (lane == 0) {
                #pragma unroll
                for (int j = 0; j < BPG; ++j) ucol[j * DPS + c_] = accE[j] + nubO[c_];
            }
        }
        __syncthreads();
        // ---- publish uf EARLY (drain overlaps za/zo compute) ----
        if (tid < 10) llc_st(pa_w + UF_O + tid * 4, *(f4*)&ucol[tid * 4]);

        // ---- za/zo partials for next step: k>=1 rows + own-final-u tap0 fold ----
        if (tid < 128) {
            int j = tid >> 5, c = tid & 31;
            float acc = 0.f;
            if (c < 30) {
                for (int dd = 0; dd < DPS; ++dd) {
                    int rg = 2 * s + (dd >= 5);
                    int of = dd * 10 - (dd >= 5 ? 50 : 0);
                    const float* xb = &xsE[j][rg * 52 + of];
                    #pragma unroll
                    for (int k = 1; k < KK; ++k) acc += xb[k] * wNa[dd * 10 + k][c];
                }
                #pragma unroll
                for (int dl = 0; dl < DPS; ++dl) acc += ucol[j * DPS + dl] * naT0[dl][c];
            }
            zr[j * 32 + c] = acc;
        }
        if (tid >= 128 && tid < 384) {
            int t = tid - 128, j = t >> 6, o = t & 63;
            float acc = 0.f;
            for (int dd = 0; dd < DPS; ++dd) {
                int rg = 2 * s + (dd >= 5);
                int of = dd * 10 - (dd >= 5 ? 50 : 0);
                const float* xb = &xsE[j][rg * 52 + of];
                #pragma unroll
                for (int k = 1; k < KK; ++k) acc += xb[k] * wNo[dd * 10 + k][o];
            }
            #pragma unroll
            for (int dl = 0; dl < DPS; ++dl) acc += ucol[j * DPS + dl] * noT0[dl][o];
            zor[j * 64 + o] = acc;
        }
        __syncthreads();

        // ---- publish za / zo, barrier (barA) ----
        if (tid >= 10 && tid < 42)  { int q = tid - 10; llc_st(pa_w + ZA_O + q * 4, *(f4*)&zr[q * 4]); }
        if (tid >= 42 && tid < 106) { int q = tid - 42; llc_st(pa_w + ZO_O + q * 4, *(f4*)&zor[q * 4]); }
        gbar8(ctr, s, 32 * (i + 2));
    }

    // ---- final output o_{T-1} (owner) ----
    if (owner) {
        const float* pa_r = pubA + (size_t)(T & 1) * HALF_A + (size_t)g * NSL * PSA;
        if (tid < 512) {
            f4 v; llc_ld(&v, pa_r + (tid >> 4) * PSA + ZO_O + s * 64 + (tid & 15) * 4);
            *(f4*)&zostage[tid >> 4][(tid & 15) * 4] = v;
        }
        __syncthreads();
        if (tid < DOUT) {
            float v = foNoL[tid];
            for (int p = 0; p < NSL; ++p) v += zostage[p][tid];
            out[((size_t)(T - 1) * BB + (g * BPG + s)) * DOUT + tid] = v;
        }
    }
}

extern "C" void kernel_launch(void* const* d_in, const int* in_sizes, int n_in,
                              void* d_out, int out_size, void* d_ws, size_t ws_size,
                              hipStream_t stream) {
    const int*   sentence = (const int*)d_in[0];
    const int*   speaker  = (const int*)d_in[1];
    const float* LutP = (const float*)d_in[2];
    const float* LutS = (const float*)d_in[3];
    const float* NaW  = (const float*)d_in[4];
    const float* NaB  = (const float*)d_in[5];
    const float* NuW  = (const float*)d_in[6];
    const float* NuB  = (const float*)d_in[7];
    const float* NoW  = (const float*)d_in[8];
    const float* NoB  = (const float*)d_in[9];
    const float* FuW  = (const float*)d_in[10];
    const float* FuB  = (const float*)d_in[11];
    const float* FoW  = (const float*)d_in[12];
    const float* FoB  = (const float*)d_in[13];
    const int*   Tptr = (const int*)d_in[14];
    float* ws   = (float*)d_ws;
    float* outp = (float*)d_out;

    hipLaunchKernelGGL(prep_kernel, dim3(2), dim3(1024), 0, stream, (int*)d_ws);
    hipLaunchKernelGGL(recur_kernel, dim3(NSL * NGR), dim3(NTH), 0, stream,
                       sentence, speaker, LutP, LutS, NaW, NaB,
                       NuW, NuB, NoW, NoB, FuW, FuB, FoW, FoB,
                       ws, Tptr, outp);
}